// Round 14
// baseline (54.373 us; speedup 1.0000x reference)
//
#include <hip/hip_runtime.h>
#include <hip/hip_bf16.h>

#define BB 2
#define DD 160
#define HH 192
#define WW 160
#define SDp (HH * WW)          // 30720

// R8 geometry: block 32(w) x 8(h), 4 d-slices/thread, halo +-3.
// Tile d [d0-3, d0+7] (11), h [hb-3, hb+11] (15), w [wb-4, wb+35] (40).
// LDS = fp16 w-pairs (R12 read path: 4 aligned b32 reads, half conflicts).
// Staging: neighbor elem via __shfl_down (no extra dword load), streamed
// load->pack->ds_write_b128, incremental index decode (row now updated too —
// R13's NaN was rows 26..164 never written).
#define TD 11
#define TH 15
#define TWf 40
#define PLANE (TH * TWf)           // 600 u32 slots
#define TILE_U (TD * PLANE)        // 6600 u32 = 26400 B -> 6 blocks/CU
#define NGRP (TD * TH * (TWf/4))   // 1650 float4-source groups
#define NITER 7                    // ceil(1650/256)

typedef __fp16 half2v __attribute__((ext_vector_type(2)));

__device__ __forceinline__ unsigned pk(float a, float b) {
    half2v h = __builtin_amdgcn_cvt_pkrtz(a, b);
    unsigned u; __builtin_memcpy(&u, &h, 4); return u;
}

__device__ __forceinline__ float2 unpk(unsigned u) {
    half2v h; __builtin_memcpy(&h, &u, 4);
    return make_float2((float)h[0], (float)h[1]);
}

__device__ __forceinline__ float2 ld2(const float* __restrict__ vb, int off) {
    float2 v;
    __builtin_memcpy(&v, vb + off, 8);   // global_load_dwordx2 (fallback path)
    return v;
}

__global__ void __launch_bounds__(256, 6)
st_trilinear_pk3(const float* __restrict__ vol,
                 const float* __restrict__ shift,
                 float* __restrict__ out) {
    __shared__ __align__(16) unsigned tile[TILE_U];

    // XCD-aware decomposition of 9600 blocks = (5 bx, 24 by, 80 z)
    int bid = blockIdx.x;
    int xcd = bid & 7;
    int rank = bid >> 3;           // 0..1199
    int zl = rank / 120;           // 0..9
    int xy = rank % 120;
    int by = xy / 5;               // 0..23
    int bx = xy - by * 5;          // 0..4
    int z = xcd * 10 + zl;         // 0..79
    int b = z / 40;
    int d0 = (z - b * 40) * 4;

    const int tid = threadIdx.y * 32 + threadIdx.x;
    const int w = bx * 32 + threadIdx.x;
    const int h = by * 8 + threadIdx.y;

    const int dlo = d0 - 3;
    const int hlo = by * 8 - 3;
    const int wlo = bx * 32 - 4;   // 16B-aligned staging sources

    const float* __restrict__ vb = vol + (long)b * (DD * SDp);
    const long idx = (((long)b * DD + d0) * HH + h) * WW + w;

    // --- shift loads first (latency overlaps staging) ---
    float3 s0, s1, s2, s3;
    __builtin_memcpy(&s0, shift + (idx + 0 * SDp) * 3, 12);
    __builtin_memcpy(&s1, shift + (idx + 1 * SDp) * 3, 12);
    __builtin_memcpy(&s2, shift + (idx + 2 * SDp) * 3, 12);
    __builtin_memcpy(&s3, shift + (idx + 3 * SDp) * 3, 12);

    // --- stage: per group load dwordx4, neighbor elem via shfl_down(1),
    //     pack 4 overlapping fp16 w-pairs, ds_write_b128.
    //     group e -> (row = e/10, c4 = (e%10)*4), row = dd*15 + hh,
    //     maintained incrementally (e += 256 -> row += 25 + carry, rem += 6).
    //     Slot 39's hi half is garbage; never read (in-tile needs wp<=wlo+38).
    //     Row-terminal groups (c4=36) wrap shfl to next row: slot 39, unread.
    //     Lane 63 patches its neighbor with a single dword load. ---
    {
        int row = tid / 10;
        int rem = tid - row * 10;
        int dd = row / 15;
        int hh = row - dd * 15;
        const int lane = tid & 63;
#pragma unroll
        for (int i = 0; i < NITER; ++i) {
            int e = i * 256 + tid;
            bool act = (e < NGRP);
            int c4 = rem << 2;
            int dsrc = min(max(dlo + dd, 0), DD - 1);
            int hsrc = min(max(hlo + hh, 0), HH - 1);
            int wsrc = min(max(wlo + c4, 0), WW - 4);
            const float* p = vb + dsrc * SDp + hsrc * WW + wsrc;
            float4 A = make_float4(0.f, 0.f, 0.f, 0.f);
            if (act) __builtin_memcpy(&A, p, 16);          // global_load_dwordx4
            float nb = __shfl_down(A.x, 1);
            if (lane == 63 && act) nb = p[min(4, WW - 1 - wsrc)];
            if (act) {
                uint4 q;
                q.x = pk(A.x, A.y);
                q.y = pk(A.y, A.z);
                q.z = pk(A.z, A.w);
                q.w = pk(A.w, nb);
                *(uint4*)&tile[row * TWf + c4] = q;        // ds_write_b128
            }
            // e += 256: rem += 6 (carry), row += 25 + carry, dd/hh tracked
            rem += 6;
            int carry = (rem >= 10);
            rem -= carry * 10;
            row += 25 + carry;
            hh += 10 + carry;
            dd += 1;
            int c2 = (hh >= 15);
            hh -= c2 * 15;
            dd += c2;
        }
    }
    __syncthreads();

    const float fd = (float)d0, fh = (float)h, fw = (float)w;

#pragma unroll
    for (int j = 0; j < 4; ++j) {
        float3 s = (j == 0) ? s0 : (j == 1) ? s1 : (j == 2) ? s2 : s3;

        float ldc = fminf(fmaxf(fd + (float)j + s.x, 0.0f), (float)(DD - 1));
        float lhc = fminf(fmaxf(fh + s.y, 0.0f), (float)(HH - 1));
        float lwc = fminf(fmaxf(fw + s.z, 0.0f), (float)(WW - 1));

        float fd0 = floorf(ldc), fh0 = floorf(lhc), fw0 = floorf(lwc);
        int d0c = (int)fd0, h0c = (int)fh0, w0c = (int)fw0;
        int d1c = min(d0c + 1, DD - 1);
        int h1c = min(h0c + 1, HH - 1);
        int wp  = min(w0c, WW - 2);          // pair trick (exact: tw==0 at edge)

        float td_ = ldc - fd0;
        float th_ = lhc - fh0;
        float tw_ = (lwc - fw0) + (float)(w0c - wp);

        float2 a00, a01, a10, a11;
        // exact in-tile test; fallback guarantees correctness for any shift
        bool ok = (d0c >= dlo) & (d1c <= dlo + TD - 1) &
                  (h0c >= hlo) & (h1c <= hlo + TH - 1) &
                  (wp >= wlo) & (wp + 1 <= wlo + TWf - 1);
        if (__builtin_expect(ok, 1)) {
            int lo  = ((d0c - dlo) * TH + (h0c - hlo)) * TWf + (wp - wlo);
            int d1l = (d1c - d0c) * PLANE;
            int h1l = (h1c - h0c) * TWf;
            a00 = unpk(tile[lo]);                 // 4x aligned ds_read_b32,
            a01 = unpk(tile[lo + h1l]);           // 1 bank per lane per read
            a10 = unpk(tile[lo + d1l]);
            a11 = unpk(tile[lo + d1l + h1l]);
        } else {
            int go = d0c * SDp + h0c * WW + wp;
            int gd = (d1c - d0c) * SDp;
            int gh = (h1c - h0c) * WW;
            a00 = ld2(vb, go);
            a01 = ld2(vb, go + gh);
            a10 = ld2(vb, go + gd);
            a11 = ld2(vb, go + gd + gh);
        }

        float x00 = a00.x + tw_ * (a00.y - a00.x);
        float x01 = a01.x + tw_ * (a01.y - a01.x);
        float x10 = a10.x + tw_ * (a10.y - a10.x);
        float x11 = a11.x + tw_ * (a11.y - a11.x);
        float y0 = x00 + th_ * (x01 - x00);
        float y1 = x10 + th_ * (x11 - x10);
        float r = y0 + td_ * (y1 - y0);

        __builtin_nontemporal_store(r, out + idx + (long)j * SDp);
    }
}

extern "C" void kernel_launch(void* const* d_in, const int* in_sizes, int n_in,
                              void* d_out, int out_size, void* d_ws, size_t ws_size,
                              hipStream_t stream) {
    const float* vol   = (const float*)d_in[0];
    const float* shift = (const float*)d_in[1];
    float* out = (float*)d_out;

    dim3 block(32, 8, 1);
    int grid = (WW / 32) * (HH / 8) * (DD / 4) * BB;   // 9600

    st_trilinear_pk3<<<grid, block, 0, stream>>>(vol, shift, out);
}

// Round 15
// 39.000 us; speedup vs baseline: 1.3942x; 1.3942x over previous
//
#include <hip/hip_runtime.h>
#include <hip/hip_bf16.h>

#define BB 2
#define DD 160
#define HH 192
#define WW 160
#define SDp (HH * WW)          // 30720

// BEST CONFIG (R8, 39.1us): block 32(w) x 8(h), 4 d-slices/thread, halo +-3.
// LDS tile d [d0-3, d0+7] (11), h [hb-3, hb+11] (15), w [wb-4, wb+35] (40).
// 6600 floats = 26400 B -> 6 blocks/CU x 4 waves = 24 waves (75% occ cap).
// Staging via async global_load_lds (f32, linear); gathers from LDS with
// exact in-tile test + global fallback (correct for any shift magnitude).
// Tested and rejected: bigger tile (R7), more occupancy (R9), fp16-packed
// LDS w-pairs (R10-R14: read-side win < reg-staging cost).
#define TD 11
#define TH 15
#define TWf 40
#define PLANE (TH * TWf)           // 600
#define TILE_F (TD * PLANE)        // 6600
#define NF4 (TILE_F / 4)           // 1650 float4 slots
#define NITER 7                    // ceil(1650/256)

__device__ __forceinline__ float2 ld2(const float* __restrict__ vb, int off) {
    float2 v;
    __builtin_memcpy(&v, vb + off, 8);   // global_load_dwordx2
    return v;
}

__device__ __forceinline__ void gload_lds16(const float* g, float* l) {
    __builtin_amdgcn_global_load_lds(
        (const __attribute__((address_space(1))) void*)g,
        (__attribute__((address_space(3))) void*)l, 16, 0, 0);
}

__global__ void __launch_bounds__(256, 6)
st_trilinear_lds3(const float* __restrict__ vol,
                  const float* __restrict__ shift,
                  float* __restrict__ out) {
    __shared__ float tile[TILE_F];

    // XCD-aware decomposition of 9600 blocks = (5 bx, 24 by, 80 z)
    int bid = blockIdx.x;
    int xcd = bid & 7;
    int rank = bid >> 3;           // 0..1199
    int zl = rank / 120;           // 0..9
    int xy = rank % 120;
    int by = xy / 5;               // 0..23
    int bx = xy - by * 5;          // 0..4
    int z = xcd * 10 + zl;         // 0..79
    int b = z / 40;
    int d0 = (z - b * 40) * 4;

    const int tid = threadIdx.y * 32 + threadIdx.x;
    const int w = bx * 32 + threadIdx.x;
    const int h = by * 8 + threadIdx.y;

    const int dlo = d0 - 3;
    const int hlo = by * 8 - 3;
    const int wlo = bx * 32 - 4;   // 16B-aligned staging sources

    const float* __restrict__ vb = vol + (long)b * (DD * SDp);
    const long idx = (((long)b * DD + d0) * HH + h) * WW + w;

    // --- shift loads first: latency hides under the staging issues ---
    float3 s0, s1, s2, s3;
    __builtin_memcpy(&s0, shift + (idx + 0 * SDp) * 3, 12);
    __builtin_memcpy(&s1, shift + (idx + 1 * SDp) * 3, 12);
    __builtin_memcpy(&s2, shift + (idx + 2 * SDp) * 3, 12);
    __builtin_memcpy(&s3, shift + (idx + 3 * SDp) * 3, 12);

    // --- stage vol tile: async global->LDS, 16B/lane, coalesced ---
    // float4 slot e <-> tile[4e]; e -> (row = e/10, c4 = (e%10)*4),
    // row = dd*15 + hh. Border slots hold clamped duplicates, never read
    // (in-tile test is exact; fallback covers everything else).
    float* lbase = tile + (tid >> 6) * 256;   // wave base (HW: base + lane*16B)
#pragma unroll
    for (int i = 0; i < NITER; ++i) {
        int e = i * 256 + tid;
        if (e < NF4) {                        // exec-masked lanes skip write
            int row = e / 10;
            int c4 = (e - row * 10) << 2;
            int dd = row / 15;
            int hh = row - dd * 15;
            int dsrc = min(max(dlo + dd, 0), DD - 1);
            int hsrc = min(max(hlo + hh, 0), HH - 1);
            int wsrc = min(max(wlo + c4, 0), WW - 4);
            gload_lds16(vb + dsrc * SDp + hsrc * WW + wsrc, lbase + i * 1024);
        }
    }
    __syncthreads();   // drains vmcnt (staging + shift)

    const float fd = (float)d0, fh = (float)h, fw = (float)w;

#pragma unroll
    for (int j = 0; j < 4; ++j) {
        float3 s = (j == 0) ? s0 : (j == 1) ? s1 : (j == 2) ? s2 : s3;

        float ldc = fminf(fmaxf(fd + (float)j + s.x, 0.0f), (float)(DD - 1));
        float lhc = fminf(fmaxf(fh + s.y, 0.0f), (float)(HH - 1));
        float lwc = fminf(fmaxf(fw + s.z, 0.0f), (float)(WW - 1));

        float fd0 = floorf(ldc), fh0 = floorf(lhc), fw0 = floorf(lwc);
        int d0c = (int)fd0, h0c = (int)fh0, w0c = (int)fw0;
        int d1c = min(d0c + 1, DD - 1);
        int h1c = min(h0c + 1, HH - 1);
        int wp  = min(w0c, WW - 2);          // pair-load (exact: tw==0 at edge)

        float td_ = ldc - fd0;
        float th_ = lhc - fh0;
        float tw_ = (lwc - fw0) + (float)(w0c - wp);

        float2 a00, a01, a10, a11;
        // exact in-tile test; fallback guarantees correctness for any shift
        bool ok = (d0c >= dlo) & (d1c <= dlo + TD - 1) &
                  (h0c >= hlo) & (h1c <= hlo + TH - 1) &
                  (wp >= wlo) & (wp + 1 <= wlo + TWf - 1);
        if (__builtin_expect(ok, 1)) {
            int lo  = ((d0c - dlo) * TH + (h0c - hlo)) * TWf + (wp - wlo);
            int d1l = (d1c - d0c) * PLANE;
            int h1l = (h1c - h0c) * TWf;
            a00 = make_float2(tile[lo], tile[lo + 1]);
            a01 = make_float2(tile[lo + h1l], tile[lo + h1l + 1]);
            a10 = make_float2(tile[lo + d1l], tile[lo + d1l + 1]);
            a11 = make_float2(tile[lo + d1l + h1l], tile[lo + d1l + h1l + 1]);
        } else {
            int go = d0c * SDp + h0c * WW + wp;
            int gd = (d1c - d0c) * SDp;
            int gh = (h1c - h0c) * WW;
            a00 = ld2(vb, go);
            a01 = ld2(vb, go + gh);
            a10 = ld2(vb, go + gd);
            a11 = ld2(vb, go + gd + gh);
        }

        float x00 = a00.x + tw_ * (a00.y - a00.x);
        float x01 = a01.x + tw_ * (a01.y - a01.x);
        float x10 = a10.x + tw_ * (a10.y - a10.x);
        float x11 = a11.x + tw_ * (a11.y - a11.x);
        float y0 = x00 + th_ * (x01 - x00);
        float y1 = x10 + th_ * (x11 - x10);
        float r = y0 + td_ * (y1 - y0);

        __builtin_nontemporal_store(r, out + idx + (long)j * SDp);
    }
}

extern "C" void kernel_launch(void* const* d_in, const int* in_sizes, int n_in,
                              void* d_out, int out_size, void* d_ws, size_t ws_size,
                              hipStream_t stream) {
    const float* vol   = (const float*)d_in[0];
    const float* shift = (const float*)d_in[1];
    float* out = (float*)d_out;

    dim3 block(32, 8, 1);
    int grid = (WW / 32) * (HH / 8) * (DD / 4) * BB;   // 9600

    st_trilinear_lds3<<<grid, block, 0, stream>>>(vol, shift, out);
}